// Round 12
// baseline (309.450 us; speedup 1.0000x reference)
//
#include <hip/hip_runtime.h>

#define C_N   512
#define E_N   261632
#define CAP   768          // bucket capacity per receiver (max count ~590)

typedef _Float16 f16;
typedef _Float16 f16x8_t __attribute__((ext_vector_type(8)));
typedef float    f32x16_t __attribute__((ext_vector_type(16)));

// ---------------- K1: everything-prep ----------------
// [0,64):   SA/RB MFMA GEMM w/ LDS-staged W1 (block = br<3b> | bc<1b> | mi<2b>)
// [64,192): W2 pack  [192,256): Wo1 pack  [256,384): Wo2 pack
// [384,448): Wo3 pack  [448]: zero scatter cursors
__global__ __launch_bounds__(256) void k_prep_all(
    const float* __restrict__ inputs, const float* __restrict__ W1,
    const float* __restrict__ b1, const float* __restrict__ W2,
    const float* __restrict__ Wo1, const float* __restrict__ Wo2, const float* __restrict__ Wo3,
    f16* __restrict__ SA, f16* __restrict__ RB, f16* __restrict__ W2p,
    f16* __restrict__ Wo1p, f16* __restrict__ Wo2p, f16* __restrict__ Wo3p,
    int* __restrict__ cnt)
{
  __shared__ f16 wt[2][256][18];   // transposed W1 slice, double-buffered (18.4 KB)
  int bid = blockIdx.x;
  int tid = threadIdx.x;
  if (bid < 64) {
    // SA/RB: out[64 rows, 256 cols] of inputs[512,256] @ W1part[256,512]
    int lane = tid & 63, w = tid >> 6;          // 4 waves
    int hlf = lane >> 5, l31 = lane & 31;
    int br = bid & 7, bc = (bid >> 3) & 1, mi = bid >> 4;
    int t = mi >> 1, half = mi & 1;
    const float* Wsrc = W1 + (size_t)t * 512 * 512 + (size_t)half * 256 * 512;

    f32x16_t acc[2][2];
    #pragma unroll
    for (int rt = 0; rt < 2; rt++)
      #pragma unroll
      for (int ctl = 0; ctl < 2; ctl++)
        #pragma unroll
        for (int r = 0; r < 16; r++) acc[rt][ctl][r] = 0.f;

    // stage kc=0 into buf 0
    #pragma unroll
    for (int i = 0; i < 4; i++) {
      int idx = tid + i * 256;                  // 0..1023
      int k = idx >> 6, n4 = idx & 63;          // 16 k x 64 n4
      float4 v = *(const float4*)&Wsrc[(size_t)k * 512 + bc * 256 + n4 * 4];
      wt[0][n4 * 4 + 0][k] = (f16)v.x;
      wt[0][n4 * 4 + 1][k] = (f16)v.y;
      wt[0][n4 * 4 + 2][k] = (f16)v.z;
      wt[0][n4 * 4 + 3][k] = (f16)v.w;
    }

    for (int kc = 0; kc < 16; kc++) {
      __syncthreads();
      if (kc + 1 < 16) {
        int b = (kc + 1) & 1;
        #pragma unroll
        for (int i = 0; i < 4; i++) {
          int idx = tid + i * 256;
          int k = idx >> 6, n4 = idx & 63;
          float4 v = *(const float4*)&Wsrc[(size_t)((kc + 1) * 16 + k) * 512 + bc * 256 + n4 * 4];
          wt[b][n4 * 4 + 0][k] = (f16)v.x;
          wt[b][n4 * 4 + 1][k] = (f16)v.y;
          wt[b][n4 * 4 + 2][k] = (f16)v.z;
          wt[b][n4 * 4 + 3][k] = (f16)v.w;
        }
      }
      f16x8_t af[2];
      #pragma unroll
      for (int rt = 0; rt < 2; rt++) {
        const float4* p = (const float4*)&inputs[(size_t)(br * 64 + rt * 32 + l31) * 256 + kc * 16 + hlf * 8];
        float4 u0 = p[0], u1 = p[1];
        af[rt] = (f16x8_t){(f16)u0.x, (f16)u0.y, (f16)u0.z, (f16)u0.w,
                           (f16)u1.x, (f16)u1.y, (f16)u1.z, (f16)u1.w};
      }
      int b = kc & 1;
      #pragma unroll
      for (int ctl = 0; ctl < 2; ctl++) {
        int n = (2 * w + ctl) * 32 + l31;       // 0..255 (local col)
        f16x8_t bfr = *(const f16x8_t*)&wt[b][n][hlf * 8];
        #pragma unroll
        for (int rt = 0; rt < 2; rt++)
          acc[rt][ctl] = __builtin_amdgcn_mfma_f32_32x32x16_f16(af[rt], bfr, acc[rt][ctl], 0, 0, 0);
      }
    }
    f16* dst = (half == 0) ? SA : RB;
    #pragma unroll
    for (int ctl = 0; ctl < 2; ctl++) {
      int col = bc * 256 + (2 * w + ctl) * 32 + l31;
      float bias = (half == 1) ? b1[t * 512 + col] : 0.f;
      #pragma unroll
      for (int rt = 0; rt < 2; rt++)
        #pragma unroll
        for (int r = 0; r < 16; r++) {
          int row = br * 64 + rt * 32 + (r & 3) + 8 * (r >> 2) + 4 * hlf;
          dst[((size_t)(t * 512 + row)) * 512 + col] = (f16)(acc[rt][ctl][r] + bias);
        }
    }
  } else if (bid < 192) {
    int gid  = (bid - 64) * 256 + tid;            // 0..32767
    int lane = gid & 63;
    int ct   = (gid >> 6) & 7;
    int kc   = (gid >> 9) & 31;
    int t    = gid >> 14;
    int n    = ct * 32 + (lane & 31);
    int k0   = kc * 16 + (lane >> 5) * 8;
    const float* src = W2 + (size_t)t * 512 * 256;
    f16x8_t v;
    #pragma unroll
    for (int j = 0; j < 8; j++) v[j] = (f16)src[(size_t)(k0 + j) * 256 + n];
    *(f16x8_t*)(W2p + (size_t)gid * 8) = v;
  } else if (bid < 256) {
    int gid  = (bid - 192) * 256 + tid;           // 0..16383
    int lane = gid & 63;
    int ct   = (gid >> 6) & 15;
    int kc   = gid >> 10;                          // 0..15
    int n    = ct * 32 + (lane & 31);
    int k0   = kc * 16 + (lane >> 5) * 8;
    f16x8_t v;
    #pragma unroll
    for (int j = 0; j < 8; j++) v[j] = (f16)Wo1[(size_t)(k0 + j) * 512 + n];
    *(f16x8_t*)(Wo1p + (size_t)gid * 8) = v;
  } else if (bid < 384) {
    int gid  = (bid - 256) * 256 + tid;           // 0..32767
    int lane = gid & 63;
    int ct   = (gid >> 6) & 15;
    int kc   = gid >> 10;                          // 0..31
    int n    = ct * 32 + (lane & 31);
    int k0   = kc * 16 + (lane >> 5) * 8;
    f16x8_t v;
    #pragma unroll
    for (int j = 0; j < 8; j++) v[j] = (f16)Wo2[(size_t)(k0 + j) * 512 + n];
    *(f16x8_t*)(Wo2p + (size_t)gid * 8) = v;
  } else if (bid < 448) {
    int gid  = (bid - 384) * 256 + tid;           // 0..16383
    int lane = gid & 63;
    int ct   = (gid >> 6) & 7;
    int kc   = gid >> 9;                           // 0..31
    int n    = ct * 32 + (lane & 31);
    int k0   = kc * 16 + (lane >> 5) * 8;
    f16x8_t v;
    #pragma unroll
    for (int j = 0; j < 8; j++) v[j] = (f16)Wo3[(size_t)(k0 + j) * 256 + n];
    *(f16x8_t*)(Wo3p + (size_t)gid * 8) = v;
  } else {
    for (int i = tid; i < 512 * 16; i += 256) cnt[i] = 0;
  }
}

// ---------------- K2: bucketed scatter, packed 8B metadata ----------------
__global__ __launch_bounds__(1024) void k_scatter_d(const int* __restrict__ rec,
    const int* __restrict__ send, const float* __restrict__ rel,
    int* __restrict__ cnt, uint2* __restrict__ smeta)
{
  __shared__ int lh[512];
  __shared__ int lb[512];
  int b = blockIdx.x;
  int e0 = b * (E_N / 64);   // 4088 exactly
  if (threadIdx.x < 512) lh[threadIdx.x] = 0;
  __syncthreads();
  for (int i = threadIdx.x; i < E_N / 64; i += 1024)
    atomicAdd(&lh[rec[e0 + i]], 1);
  __syncthreads();
  if (threadIdx.x < 512) {
    int c = lh[threadIdx.x];
    lb[threadIdx.x] = c ? atomicAdd(&cnt[threadIdx.x * 16], c) : 0;
    lh[threadIdx.x] = 0;
  }
  __syncthreads();
  for (int i = threadIdx.x; i < E_N / 64; i += 1024) {
    int e = e0 + i;
    int r = rec[e];
    int p = r * CAP + lb[r] + atomicAdd(&lh[r], 1);
    f16 r0 = (f16)rel[2 * (size_t)e];
    f16 r1 = (f16)rel[2 * (size_t)e + 1];
    unsigned pk = ((unsigned)__builtin_bit_cast(unsigned short, r1) << 16)
                |  (unsigned)__builtin_bit_cast(unsigned short, r0);
    smeta[p] = make_uint2((unsigned)send[e], pk);
  }
}

// ---------------- K3: edge MLP + aggregation (R9-R11 structure, packed meta) ----------------
#define H1S2 264

__global__ __launch_bounds__(512, 4) void k_edges(
    const f16* __restrict__ SA, const f16* __restrict__ RB,
    const f16* __restrict__ W2p, const float* __restrict__ b2,
    const uint2* __restrict__ smeta, const int* __restrict__ cnt,
    float* __restrict__ agg)
{
  __shared__ f16   h1[128 * H1S2];
  __shared__ f16   rbs[2][512];
  __shared__ float b2s[2][256];
  __shared__ float aggL[256];
  __shared__ float relv2[2][128][2];
  __shared__ int   sends2[2][128];

  int c    = blockIdx.x;
  int tid  = threadIdx.x;
  int lane = tid & 63;
  int w    = tid >> 6;
  int hlf  = lane >> 5;
  int l31  = lane & 31;
  int q5   = tid & 31;
  int rb0  = tid >> 5;

  if (tid < 128) {
    int t = tid >> 6, qq = tid & 63;
    *(f16x8_t*)&rbs[t][qq * 8] = *(const f16x8_t*)&RB[((size_t)(t * 512 + c)) * 512 + qq * 8];
  }
  if (tid < 256) aggL[tid] = 0.0f;
  { int t = (tid >> 8) & 1, col = tid & 255; b2s[t][col] = b2[t * 256 + col]; }

  int s0 = c * CAP;
  int s1 = s0 + cnt[c * 16];
  int nt = (s1 - s0 + 127) >> 7;

  if (nt > 0 && tid < 128) {
    int pos = s0 + tid;
    if (pos < s1) {
      uint2 m = smeta[pos];
      sends2[0][tid] = (int)m.x;
      relv2[0][tid][0] = (float)__builtin_bit_cast(f16, (unsigned short)(m.y & 0xffffu));
      relv2[0][tid][1] = (float)__builtin_bit_cast(f16, (unsigned short)(m.y >> 16));
    } else {
      sends2[0][tid] = 0; relv2[0][tid][0] = 0.f; relv2[0][tid][1] = 0.f;
    }
  }
  __syncthreads();

  f16x8_t g[8];
  const f16x8_t* SAc = (const f16x8_t*)SA;
  const f16x8_t* Bp  = (const f16x8_t*)W2p;
  f32x16_t acc[4];

  if (nt > 0) {
    #pragma unroll
    for (int j = 0; j < 8; j++)
      g[j] = SAc[(size_t)sends2[0][rb0 + 16 * j] * 64 + q5];
  }

  for (int ph = 0; ph < 4 * nt; ph++) {
    int ti  = ph >> 2;
    int t   = (ph >> 1) & 1;
    int kh  = ph & 1;
    int cb  = ti & 1;
    int nb  = cb ^ 1;
    bool more = (ti + 1 < nt);

    {
      f16x8_t rbq = *(const f16x8_t*)&rbs[t][(kh * 32 + q5) * 8];
      #pragma unroll
      for (int j = 0; j < 8; j++) {
        int row = rb0 + 16 * j;
        f16x8_t hv;
        #pragma unroll
        for (int e = 0; e < 8; e++) {
          f16 v = (f16)(g[j][e] + rbq[e]);
          hv[e] = (v > (f16)0.0f) ? v : (f16)0.0f;
        }
        *(f16x8_t*)&h1[row * H1S2 + q5 * 8] = hv;
      }
    }
    __syncthreads();

    if (t == 0 && kh == 0 && more && tid < 128) {
      int pos = s0 + (ti + 1) * 128 + tid;
      if (pos < s1) {
        uint2 m = smeta[pos];
        sends2[nb][tid] = (int)m.x;
        relv2[nb][tid][0] = (float)__builtin_bit_cast(f16, (unsigned short)(m.y & 0xffffu));
        relv2[nb][tid][1] = (float)__builtin_bit_cast(f16, (unsigned short)(m.y >> 16));
      } else {
        sends2[nb][tid] = 0; relv2[nb][tid][0] = 0.f; relv2[nb][tid][1] = 0.f;
      }
    }

    if (kh == 0) {
      #pragma unroll
      for (int rt = 0; rt < 4; rt++)
        #pragma unroll
        for (int r = 0; r < 16; r++) acc[rt][r] = 0.f;
    }

    f16x8_t bb[2];
    bb[0] = Bp[(size_t)(((t * 32 + kh * 16 + 0) * 8 + w) * 64 + lane)];
    bb[1] = Bp[(size_t)(((t * 32 + kh * 16 + 1) * 8 + w) * 64 + lane)];

    if (kh == 0) {
      #pragma unroll
      for (int j = 0; j < 8; j++)
        g[j] = SAc[(size_t)(t * 512 + sends2[cb][rb0 + 16 * j]) * 64 + 32 + q5];
    } else if (t == 0) {
      #pragma unroll
      for (int j = 0; j < 8; j++)
        g[j] = SAc[(size_t)(512 + sends2[cb][rb0 + 16 * j]) * 64 + q5];
    } else if (more) {
      #pragma unroll
      for (int j = 0; j < 8; j++)
        g[j] = SAc[(size_t)sends2[nb][rb0 + 16 * j] * 64 + q5];
    }

    for (int kc = 0; kc < 16; kc++) {
      int pb = kc & 1;
      #pragma unroll
      for (int rt = 0; rt < 4; rt++) {
        f16x8_t af = *(const f16x8_t*)&h1[(rt * 32 + l31) * H1S2 + kc * 16 + hlf * 8];
        acc[rt] = __builtin_amdgcn_mfma_f32_32x32x16_f16(af, bb[pb], acc[rt], 0, 0, 0);
      }
      if (kc + 2 < 16)
        bb[pb] = Bp[(size_t)(((t * 32 + kh * 16 + kc + 2) * 8 + w) * 64 + lane)];
    }

    if (kh == 1) {
      int col = w * 32 + l31;
      float b2c = b2s[t][col];
      float csum = 0.0f;
      #pragma unroll
      for (int rt = 0; rt < 4; rt++)
        #pragma unroll
        for (int r = 0; r < 16; r++) {
          int row = rt * 32 + (r & 3) + 8 * (r >> 2) + 4 * hlf;
          float v = fmaxf(acc[rt][r] + b2c, 0.0f);
          csum += v * relv2[cb][row][t];
        }
      csum += __shfl_xor(csum, 32, 64);
      if (hlf == 0) aggL[col] += csum;
    }
    __syncthreads();
  }

  if (tid < 256) agg[(size_t)c * 256 + tid] = aggL[tid];
}

// ---------------- K4: fused output MLP ----------------
#define HOS 520

__global__ __launch_bounds__(512, 1) void k_omlp(const float* __restrict__ agg,
    const f16* __restrict__ Wo1p, const float* __restrict__ bo1,
    const f16* __restrict__ Wo2p, const float* __restrict__ bo2,
    const f16* __restrict__ Wo3p, const float* __restrict__ bo3,
    float* __restrict__ out)
{
  __shared__ f16 hL1[64 * HOS];
  __shared__ f16 hL2[64 * HOS];
  int tid = threadIdx.x, lane = tid & 63, w = tid >> 6;
  int hlf = lane >> 5, l31 = lane & 31;
  int br = blockIdx.x;

  {
    f32x16_t acc[2][2];
    #pragma unroll
    for (int rt = 0; rt < 2; rt++)
      #pragma unroll
      for (int ctl = 0; ctl < 2; ctl++)
        #pragma unroll
        for (int r = 0; r < 16; r++) acc[rt][ctl][r] = 0.f;
    for (int kc = 0; kc < 16; kc++) {
      f16x8_t af[2];
      #pragma unroll
      for (int rt = 0; rt < 2; rt++) {
        const float4* p = (const float4*)&agg[(size_t)(br * 64 + rt * 32 + l31) * 256 + kc * 16 + hlf * 8];
        float4 u0 = p[0], u1 = p[1];
        af[rt] = (f16x8_t){(f16)u0.x, (f16)u0.y, (f16)u0.z, (f16)u0.w,
                           (f16)u1.x, (f16)u1.y, (f16)u1.z, (f16)u1.w};
      }
      #pragma unroll
      for (int ctl = 0; ctl < 2; ctl++) {
        int ct = 2 * w + ctl;
        f16x8_t bfr = *(const f16x8_t*)&Wo1p[((size_t)(kc * 16 + ct) * 64 + lane) * 8];
        #pragma unroll
        for (int rt = 0; rt < 2; rt++)
          acc[rt][ctl] = __builtin_amdgcn_mfma_f32_32x32x16_f16(af[rt], bfr, acc[rt][ctl], 0, 0, 0);
      }
    }
    #pragma unroll
    for (int ctl = 0; ctl < 2; ctl++) {
      int col = (2 * w + ctl) * 32 + l31;
      float bias = bo1[col];
      #pragma unroll
      for (int rt = 0; rt < 2; rt++)
        #pragma unroll
        for (int r = 0; r < 16; r++) {
          int row = rt * 32 + (r & 3) + 8 * (r >> 2) + 4 * hlf;
          hL1[row * HOS + col] = (f16)fmaxf(acc[rt][ctl][r] + bias, 0.f);
        }
    }
  }
  __syncthreads();

  {
    f32x16_t acc[2][2];
    #pragma unroll
    for (int rt = 0; rt < 2; rt++)
      #pragma unroll
      for (int ctl = 0; ctl < 2; ctl++)
        #pragma unroll
        for (int r = 0; r < 16; r++) acc[rt][ctl][r] = 0.f;
    for (int kc = 0; kc < 32; kc++) {
      f16x8_t af[2];
      #pragma unroll
      for (int rt = 0; rt < 2; rt++)
        af[rt] = *(const f16x8_t*)&hL1[(rt * 32 + l31) * HOS + kc * 16 + hlf * 8];
      #pragma unroll
      for (int ctl = 0; ctl < 2; ctl++) {
        int ct = 2 * w + ctl;
        f16x8_t bfr = *(const f16x8_t*)&Wo2p[((size_t)(kc * 16 + ct) * 64 + lane) * 8];
        #pragma unroll
        for (int rt = 0; rt < 2; rt++)
          acc[rt][ctl] = __builtin_amdgcn_mfma_f32_32x32x16_f16(af[rt], bfr, acc[rt][ctl], 0, 0, 0);
      }
    }
    #pragma unroll
    for (int ctl = 0; ctl < 2; ctl++) {
      int col = (2 * w + ctl) * 32 + l31;
      float bias = bo2[col];
      #pragma unroll
      for (int rt = 0; rt < 2; rt++)
        #pragma unroll
        for (int r = 0; r < 16; r++) {
          int row = rt * 32 + (r & 3) + 8 * (r >> 2) + 4 * hlf;
          hL2[row * HOS + col] = (f16)fmaxf(acc[rt][ctl][r] + bias, 0.f);
        }
    }
  }
  __syncthreads();

  {
    f32x16_t acc[2];
    #pragma unroll
    for (int rt = 0; rt < 2; rt++)
      #pragma unroll
      for (int r = 0; r < 16; r++) acc[rt][r] = 0.f;
    for (int kc = 0; kc < 32; kc++) {
      f16x8_t bfr = *(const f16x8_t*)&Wo3p[((size_t)(kc * 8 + w) * 64 + lane) * 8];
      #pragma unroll
      for (int rt = 0; rt < 2; rt++) {
        f16x8_t af = *(const f16x8_t*)&hL2[(rt * 32 + l31) * HOS + kc * 16 + hlf * 8];
        acc[rt] = __builtin_amdgcn_mfma_f32_32x32x16_f16(af, bfr, acc[rt], 0, 0, 0);
      }
    }
    int col = w * 32 + l31;
    float bias = bo3[col];
    #pragma unroll
    for (int rt = 0; rt < 2; rt++)
      #pragma unroll
      for (int r = 0; r < 16; r++) {
        int row = br * 64 + rt * 32 + (r & 3) + 8 * (r >> 2) + 4 * hlf;
        out[(size_t)row * 256 + col] = acc[rt][r] + bias;
      }
  }
}

// ---------------- launcher ----------------
extern "C" void kernel_launch(void* const* d_in, const int* in_sizes, int n_in,
                              void* d_out, int out_size, void* d_ws, size_t ws_size,
                              hipStream_t stream)
{
  (void)in_sizes; (void)n_in; (void)out_size; (void)ws_size;
  const float* inputs = (const float*)d_in[0];
  const float* rel    = (const float*)d_in[1];
  const float* W1     = (const float*)d_in[2];
  const float* b1     = (const float*)d_in[3];
  const float* W2     = (const float*)d_in[4];
  const float* b2     = (const float*)d_in[5];
  const float* Wo1    = (const float*)d_in[6];
  const float* bo1    = (const float*)d_in[7];
  const float* Wo2    = (const float*)d_in[8];
  const float* bo2    = (const float*)d_in[9];
  const float* Wo3    = (const float*)d_in[10];
  const float* bo3    = (const float*)d_in[11];
  const int* send_idx = (const int*)d_in[12];
  const int* rec_idx  = (const int*)d_in[13];
  float* out = (float*)d_out;

  char* ws = (char*)d_ws;
  f16*    SA    = (f16*)   (ws);                   // 1 MB
  f16*    RB    = (f16*)   (ws + (1024u << 10));   // 1 MB
  f16*    W2p   = (f16*)   (ws + (2048u << 10));   // 512 KB
  float*  agg   = (float*) (ws + (2560u << 10));   // 512 KB
  int*    cnt   = (int*)   (ws + (3072u << 10));   // 32 KB
  f16*    Wo1p  = (f16*)   (ws + (3136u << 10));   // 256 KB
  f16*    Wo2p  = (f16*)   (ws + (3392u << 10));   // 512 KB
  f16*    Wo3p  = (f16*)   (ws + (3904u << 10));   // 256 KB
  uint2*  smeta = (uint2*) (ws + (4160u << 10));   // 3 MB (512*768*8) -> total ~7.2 MB

  k_prep_all <<<dim3(449), dim3(256),  0, stream>>>(inputs, W1, b1, W2, Wo1, Wo2, Wo3,
                                                    SA, RB, W2p, Wo1p, Wo2p, Wo3p, cnt);
  k_scatter_d<<<dim3(64),  dim3(1024), 0, stream>>>(rec_idx, send_idx, rel, cnt, smeta);
  k_edges    <<<dim3(512), dim3(512),  0, stream>>>(SA, RB, W2p, b2, smeta, cnt, agg);
  k_omlp     <<<dim3(8),   dim3(512),  0, stream>>>(agg, Wo1p, bo1, Wo2p, bo2, Wo3p, bo3, out);
}

// Round 13
// 291.723 us; speedup vs baseline: 1.0608x; 1.0608x over previous
//
#include <hip/hip_runtime.h>

#define C_N   512
#define E_N   261632
#define CAP   768          // bucket capacity per receiver (max count ~590)

typedef _Float16 f16;
typedef _Float16 f16x8_t __attribute__((ext_vector_type(8)));
typedef float    f32x16_t __attribute__((ext_vector_type(16)));

// ---------------- K1: everything-prep ----------------
// [0,64):   SA/RB MFMA GEMM w/ LDS-staged W1
// [64,192): W2 pack  [192,256): Wo1 pack  [256,384): Wo2 pack
// [384,448): Wo3 pack  [448]: zero cnt  [449]: zero agg
__global__ __launch_bounds__(256) void k_prep_all(
    const float* __restrict__ inputs, const float* __restrict__ W1,
    const float* __restrict__ b1, const float* __restrict__ W2,
    const float* __restrict__ Wo1, const float* __restrict__ Wo2, const float* __restrict__ Wo3,
    f16* __restrict__ SA, f16* __restrict__ RB, f16* __restrict__ W2p,
    f16* __restrict__ Wo1p, f16* __restrict__ Wo2p, f16* __restrict__ Wo3p,
    int* __restrict__ cnt, float* __restrict__ agg)
{
  __shared__ f16 wt[2][256][18];
  int bid = blockIdx.x;
  int tid = threadIdx.x;
  if (bid < 64) {
    int lane = tid & 63, w = tid >> 6;
    int hlf = lane >> 5, l31 = lane & 31;
    int br = bid & 7, bc = (bid >> 3) & 1, mi = bid >> 4;
    int t = mi >> 1, half = mi & 1;
    const float* Wsrc = W1 + (size_t)t * 512 * 512 + (size_t)half * 256 * 512;

    f32x16_t acc[2][2];
    #pragma unroll
    for (int rt = 0; rt < 2; rt++)
      #pragma unroll
      for (int ctl = 0; ctl < 2; ctl++)
        #pragma unroll
        for (int r = 0; r < 16; r++) acc[rt][ctl][r] = 0.f;

    #pragma unroll
    for (int i = 0; i < 4; i++) {
      int idx = tid + i * 256;
      int k = idx >> 6, n4 = idx & 63;
      float4 v = *(const float4*)&Wsrc[(size_t)k * 512 + bc * 256 + n4 * 4];
      wt[0][n4 * 4 + 0][k] = (f16)v.x;
      wt[0][n4 * 4 + 1][k] = (f16)v.y;
      wt[0][n4 * 4 + 2][k] = (f16)v.z;
      wt[0][n4 * 4 + 3][k] = (f16)v.w;
    }

    for (int kc = 0; kc < 16; kc++) {
      __syncthreads();
      if (kc + 1 < 16) {
        int b = (kc + 1) & 1;
        #pragma unroll
        for (int i = 0; i < 4; i++) {
          int idx = tid + i * 256;
          int k = idx >> 6, n4 = idx & 63;
          float4 v = *(const float4*)&Wsrc[(size_t)((kc + 1) * 16 + k) * 512 + bc * 256 + n4 * 4];
          wt[b][n4 * 4 + 0][k] = (f16)v.x;
          wt[b][n4 * 4 + 1][k] = (f16)v.y;
          wt[b][n4 * 4 + 2][k] = (f16)v.z;
          wt[b][n4 * 4 + 3][k] = (f16)v.w;
        }
      }
      f16x8_t af[2];
      #pragma unroll
      for (int rt = 0; rt < 2; rt++) {
        const float4* p = (const float4*)&inputs[(size_t)(br * 64 + rt * 32 + l31) * 256 + kc * 16 + hlf * 8];
        float4 u0 = p[0], u1 = p[1];
        af[rt] = (f16x8_t){(f16)u0.x, (f16)u0.y, (f16)u0.z, (f16)u0.w,
                           (f16)u1.x, (f16)u1.y, (f16)u1.z, (f16)u1.w};
      }
      int b = kc & 1;
      #pragma unroll
      for (int ctl = 0; ctl < 2; ctl++) {
        int n = (2 * w + ctl) * 32 + l31;
        f16x8_t bfr = *(const f16x8_t*)&wt[b][n][hlf * 8];
        #pragma unroll
        for (int rt = 0; rt < 2; rt++)
          acc[rt][ctl] = __builtin_amdgcn_mfma_f32_32x32x16_f16(af[rt], bfr, acc[rt][ctl], 0, 0, 0);
      }
    }
    f16* dst = (half == 0) ? SA : RB;
    #pragma unroll
    for (int ctl = 0; ctl < 2; ctl++) {
      int col = bc * 256 + (2 * w + ctl) * 32 + l31;
      float bias = (half == 1) ? b1[t * 512 + col] : 0.f;
      #pragma unroll
      for (int rt = 0; rt < 2; rt++)
        #pragma unroll
        for (int r = 0; r < 16; r++) {
          int row = br * 64 + rt * 32 + (r & 3) + 8 * (r >> 2) + 4 * hlf;
          dst[((size_t)(t * 512 + row)) * 512 + col] = (f16)(acc[rt][ctl][r] + bias);
        }
    }
  } else if (bid < 192) {
    int gid  = (bid - 64) * 256 + tid;
    int lane = gid & 63;
    int ct   = (gid >> 6) & 7;
    int kc   = (gid >> 9) & 31;
    int t    = gid >> 14;
    int n    = ct * 32 + (lane & 31);
    int k0   = kc * 16 + (lane >> 5) * 8;
    const float* src = W2 + (size_t)t * 512 * 256;
    f16x8_t v;
    #pragma unroll
    for (int j = 0; j < 8; j++) v[j] = (f16)src[(size_t)(k0 + j) * 256 + n];
    *(f16x8_t*)(W2p + (size_t)gid * 8) = v;
  } else if (bid < 256) {
    int gid  = (bid - 192) * 256 + tid;
    int lane = gid & 63;
    int ct   = (gid >> 6) & 15;
    int kc   = gid >> 10;
    int n    = ct * 32 + (lane & 31);
    int k0   = kc * 16 + (lane >> 5) * 8;
    f16x8_t v;
    #pragma unroll
    for (int j = 0; j < 8; j++) v[j] = (f16)Wo1[(size_t)(k0 + j) * 512 + n];
    *(f16x8_t*)(Wo1p + (size_t)gid * 8) = v;
  } else if (bid < 384) {
    int gid  = (bid - 256) * 256 + tid;
    int lane = gid & 63;
    int ct   = (gid >> 6) & 15;
    int kc   = gid >> 10;
    int n    = ct * 32 + (lane & 31);
    int k0   = kc * 16 + (lane >> 5) * 8;
    f16x8_t v;
    #pragma unroll
    for (int j = 0; j < 8; j++) v[j] = (f16)Wo2[(size_t)(k0 + j) * 512 + n];
    *(f16x8_t*)(Wo2p + (size_t)gid * 8) = v;
  } else if (bid < 448) {
    int gid  = (bid - 384) * 256 + tid;
    int lane = gid & 63;
    int ct   = (gid >> 6) & 7;
    int kc   = gid >> 9;
    int n    = ct * 32 + (lane & 31);
    int k0   = kc * 16 + (lane >> 5) * 8;
    f16x8_t v;
    #pragma unroll
    for (int j = 0; j < 8; j++) v[j] = (f16)Wo3[(size_t)(k0 + j) * 256 + n];
    *(f16x8_t*)(Wo3p + (size_t)gid * 8) = v;
  } else if (bid == 448) {
    for (int i = tid; i < 512 * 16; i += 256) cnt[i] = 0;
  } else {
    float4* a4 = (float4*)agg;
    for (int i = tid; i < 512 * 64; i += 256) a4[i] = make_float4(0.f, 0.f, 0.f, 0.f);
  }
}

// ---------------- K2: bucketed scatter, packed 8B metadata (128 blocks) ----------------
__global__ __launch_bounds__(512) void k_scatter_d(const int* __restrict__ rec,
    const int* __restrict__ send, const float* __restrict__ rel,
    int* __restrict__ cnt, uint2* __restrict__ smeta)
{
  __shared__ int lh[512];
  __shared__ int lb[512];
  int b = blockIdx.x;
  int e0 = b * (E_N / 128);   // 2044 exactly
  lh[threadIdx.x] = 0;
  __syncthreads();
  for (int i = threadIdx.x; i < E_N / 128; i += 512)
    atomicAdd(&lh[rec[e0 + i]], 1);
  __syncthreads();
  {
    int c = lh[threadIdx.x];
    lb[threadIdx.x] = c ? atomicAdd(&cnt[threadIdx.x * 16], c) : 0;
    lh[threadIdx.x] = 0;
  }
  __syncthreads();
  for (int i = threadIdx.x; i < E_N / 128; i += 512) {
    int e = e0 + i;
    int r = rec[e];
    int p = r * CAP + lb[r] + atomicAdd(&lh[r], 1);
    f16 r0 = (f16)rel[2 * (size_t)e];
    f16 r1 = (f16)rel[2 * (size_t)e + 1];
    unsigned pk = ((unsigned)__builtin_bit_cast(unsigned short, r1) << 16)
                |  (unsigned)__builtin_bit_cast(unsigned short, r0);
    smeta[p] = make_uint2((unsigned)send[e], pk);
  }
}

// ---------------- K3: edge MLP, ONE 128-edge tile per block ----------------
#define H1S2 264

__global__ __launch_bounds__(512, 4) void k_edges(
    const f16* __restrict__ SA, const f16* __restrict__ RB,
    const f16* __restrict__ W2p, const float* __restrict__ b2,
    const uint2* __restrict__ smeta, const int* __restrict__ cnt,
    float* __restrict__ agg)
{
  __shared__ f16   h1[128 * H1S2];    // 67584 B
  __shared__ f16   rbs[2][512];       // 2048 B
  __shared__ float b2s[2][256];       // 2048 B
  __shared__ float aggL[256];         // 1024 B
  __shared__ float relv[128][2];      // 1024 B
  __shared__ int   sends[128];        // 512 B  (~74 KB -> 2 blocks/CU)

  int c   = blockIdx.x;
  int ti  = blockIdx.y;
  int n_c = cnt[c * 16];
  if (ti * 128 >= n_c) return;        // empty tile -> whole block exits

  int tid  = threadIdx.x;
  int lane = tid & 63;
  int w    = tid >> 6;
  int hlf  = lane >> 5;
  int l31  = lane & 31;
  int q5   = tid & 31;
  int rb0  = tid >> 5;

  if (tid < 128) {
    int t = tid >> 6, qq = tid & 63;
    *(f16x8_t*)&rbs[t][qq * 8] = *(const f16x8_t*)&RB[((size_t)(t * 512 + c)) * 512 + qq * 8];
  }
  if (tid < 256) aggL[tid] = 0.0f;
  { int t = (tid >> 8) & 1, col = tid & 255; b2s[t][col] = b2[t * 256 + col]; }

  int s0 = c * CAP + ti * 128;
  int nv = n_c - ti * 128; if (nv > 128) nv = 128;   // valid edges this tile

  if (tid < 128) {
    if (tid < nv) {
      uint2 m = smeta[s0 + tid];
      sends[tid] = (int)m.x;
      relv[tid][0] = (float)__builtin_bit_cast(f16, (unsigned short)(m.y & 0xffffu));
      relv[tid][1] = (float)__builtin_bit_cast(f16, (unsigned short)(m.y >> 16));
    } else {
      sends[tid] = 0; relv[tid][0] = 0.f; relv[tid][1] = 0.f;
    }
  }
  __syncthreads();

  f16x8_t g[8];
  const f16x8_t* SAc = (const f16x8_t*)SA;
  const f16x8_t* Bp  = (const f16x8_t*)W2p;
  f32x16_t acc[4];

  #pragma unroll
  for (int j = 0; j < 8; j++)
    g[j] = SAc[(size_t)sends[rb0 + 16 * j] * 64 + q5];   // (t=0, kh=0)

  for (int ph = 0; ph < 4; ph++) {
    int t  = ph >> 1;
    int kh = ph & 1;

    // build h1 half-slice from prefetched g
    {
      f16x8_t rbq = *(const f16x8_t*)&rbs[t][(kh * 32 + q5) * 8];
      #pragma unroll
      for (int j = 0; j < 8; j++) {
        int row = rb0 + 16 * j;
        f16x8_t hv;
        #pragma unroll
        for (int e = 0; e < 8; e++) {
          f16 v = (f16)(g[j][e] + rbq[e]);
          hv[e] = (v > (f16)0.0f) ? v : (f16)0.0f;
        }
        *(f16x8_t*)&h1[row * H1S2 + q5 * 8] = hv;
      }
    }
    __syncthreads();

    if (kh == 0) {
      #pragma unroll
      for (int rt = 0; rt < 4; rt++)
        #pragma unroll
        for (int r = 0; r < 16; r++) acc[rt][r] = 0.f;
    }

    f16x8_t bb[2];
    bb[0] = Bp[(size_t)(((t * 32 + kh * 16 + 0) * 8 + w) * 64 + lane)];
    bb[1] = Bp[(size_t)(((t * 32 + kh * 16 + 1) * 8 + w) * 64 + lane)];

    // prefetch next phase's gather (after initial B loads; FIFO keeps in flight)
    if (ph < 3) {
      int tn  = (ph + 1) >> 1;
      int khn = (ph + 1) & 1;
      #pragma unroll
      for (int j = 0; j < 8; j++)
        g[j] = SAc[(size_t)(tn * 512 + sends[rb0 + 16 * j]) * 64 + khn * 32 + q5];
    }

    for (int kc = 0; kc < 16; kc++) {
      int pb = kc & 1;
      #pragma unroll
      for (int rt = 0; rt < 4; rt++) {
        f16x8_t af = *(const f16x8_t*)&h1[(rt * 32 + l31) * H1S2 + kc * 16 + hlf * 8];
        acc[rt] = __builtin_amdgcn_mfma_f32_32x32x16_f16(af, bb[pb], acc[rt], 0, 0, 0);
      }
      if (kc + 2 < 16)
        bb[pb] = Bp[(size_t)(((t * 32 + kh * 16 + kc + 2) * 8 + w) * 64 + lane)];
    }

    if (kh == 1) {
      int col = w * 32 + l31;
      float b2c = b2s[t][col];
      float csum = 0.0f;
      #pragma unroll
      for (int rt = 0; rt < 4; rt++)
        #pragma unroll
        for (int r = 0; r < 16; r++) {
          int row = rt * 32 + (r & 3) + 8 * (r >> 2) + 4 * hlf;
          float v = fmaxf(acc[rt][r] + b2c, 0.0f);
          csum += v * relv[row][t];
        }
      csum += __shfl_xor(csum, 32, 64);
      if (hlf == 0) aggL[col] += csum;
    }
    __syncthreads();
  }

  if (tid < 256) atomicAdd(&agg[(size_t)c * 256 + tid], aggL[tid]);
}

// ---------------- K4: fused output MLP (16 blocks x 32 rows) ----------------
#define HOS 520

__global__ __launch_bounds__(512, 1) void k_omlp(const float* __restrict__ agg,
    const f16* __restrict__ Wo1p, const float* __restrict__ bo1,
    const f16* __restrict__ Wo2p, const float* __restrict__ bo2,
    const f16* __restrict__ Wo3p, const float* __restrict__ bo3,
    float* __restrict__ out)
{
  __shared__ f16 hL1[32 * HOS];   // 33280 B
  __shared__ f16 hL2[32 * HOS];   // 33280 B
  int tid = threadIdx.x, lane = tid & 63, w = tid >> 6;
  int hlf = lane >> 5, l31 = lane & 31;
  int br = blockIdx.x;            // 32 rows per block

  // layer 1: rows 32, cols 512 (8 waves x 2 ct)
  {
    f32x16_t acc[2];
    #pragma unroll
    for (int ctl = 0; ctl < 2; ctl++)
      #pragma unroll
      for (int r = 0; r < 16; r++) acc[ctl][r] = 0.f;
    for (int kc = 0; kc < 16; kc++) {
      const float4* p = (const float4*)&agg[(size_t)(br * 32 + l31) * 256 + kc * 16 + hlf * 8];
      float4 u0 = p[0], u1 = p[1];
      f16x8_t af = (f16x8_t){(f16)u0.x, (f16)u0.y, (f16)u0.z, (f16)u0.w,
                             (f16)u1.x, (f16)u1.y, (f16)u1.z, (f16)u1.w};
      #pragma unroll
      for (int ctl = 0; ctl < 2; ctl++) {
        int ct = 2 * w + ctl;
        f16x8_t bfr = *(const f16x8_t*)&Wo1p[((size_t)(kc * 16 + ct) * 64 + lane) * 8];
        acc[ctl] = __builtin_amdgcn_mfma_f32_32x32x16_f16(af, bfr, acc[ctl], 0, 0, 0);
      }
    }
    #pragma unroll
    for (int ctl = 0; ctl < 2; ctl++) {
      int col = (2 * w + ctl) * 32 + l31;
      float bias = bo1[col];
      #pragma unroll
      for (int r = 0; r < 16; r++) {
        int row = (r & 3) + 8 * (r >> 2) + 4 * hlf;
        hL1[row * HOS + col] = (f16)fmaxf(acc[ctl][r] + bias, 0.f);
      }
    }
  }
  __syncthreads();

  // layer 2: rows 32, cols 512
  {
    f32x16_t acc[2];
    #pragma unroll
    for (int ctl = 0; ctl < 2; ctl++)
      #pragma unroll
      for (int r = 0; r < 16; r++) acc[ctl][r] = 0.f;
    for (int kc = 0; kc < 32; kc++) {
      f16x8_t af = *(const f16x8_t*)&hL1[l31 * HOS + kc * 16 + hlf * 8];
      #pragma unroll
      for (int ctl = 0; ctl < 2; ctl++) {
        int ct = 2 * w + ctl;
        f16x8_t bfr = *(const f16x8_t*)&Wo2p[((size_t)(kc * 16 + ct) * 64 + lane) * 8];
        acc[ctl] = __builtin_amdgcn_mfma_f32_32x32x16_f16(af, bfr, acc[ctl], 0, 0, 0);
      }
    }
    #pragma unroll
    for (int ctl = 0; ctl < 2; ctl++) {
      int col = (2 * w + ctl) * 32 + l31;
      float bias = bo2[col];
      #pragma unroll
      for (int r = 0; r < 16; r++) {
        int row = (r & 3) + 8 * (r >> 2) + 4 * hlf;
        hL2[row * HOS + col] = (f16)fmaxf(acc[ctl][r] + bias, 0.f);
      }
    }
  }
  __syncthreads();

  // layer 3: rows 32, cols 256 (8 waves x 1 ct)
  {
    f32x16_t acc;
    #pragma unroll
    for (int r = 0; r < 16; r++) acc[r] = 0.f;
    for (int kc = 0; kc < 32; kc++) {
      f16x8_t af  = *(const f16x8_t*)&hL2[l31 * HOS + kc * 16 + hlf * 8];
      f16x8_t bfr = *(const f16x8_t*)&Wo3p[((size_t)(kc * 8 + w) * 64 + lane) * 8];
      acc = __builtin_amdgcn_mfma_f32_32x32x16_f16(af, bfr, acc, 0, 0, 0);
    }
    int col = w * 32 + l31;
    float bias = bo3[col];
    #pragma unroll
    for (int r = 0; r < 16; r++) {
      int row = br * 32 + (r & 3) + 8 * (r >> 2) + 4 * hlf;
      out[(size_t)row * 256 + col] = acc[r] + bias;
    }
  }
}

// ---------------- launcher ----------------
extern "C" void kernel_launch(void* const* d_in, const int* in_sizes, int n_in,
                              void* d_out, int out_size, void* d_ws, size_t ws_size,
                              hipStream_t stream)
{
  (void)in_sizes; (void)n_in; (void)out_size; (void)ws_size;
  const float* inputs = (const float*)d_in[0];
  const float* rel    = (const float*)d_in[1];
  const float* W1     = (const float*)d_in[2];
  const float* b1     = (const float*)d_in[3];
  const float* W2     = (const float*)d_in[4];
  const float* b2     = (const float*)d_in[5];
  const float* Wo1    = (const float*)d_in[6];
  const float* bo1    = (const float*)d_in[7];
  const float* Wo2    = (const float*)d_in[8];
  const float* bo2    = (const float*)d_in[9];
  const float* Wo3    = (const float*)d_in[10];
  const float* bo3    = (const float*)d_in[11];
  const int* send_idx = (const int*)d_in[12];
  const int* rec_idx  = (const int*)d_in[13];
  float* out = (float*)d_out;

  char* ws = (char*)d_ws;
  f16*    SA    = (f16*)   (ws);                   // 1 MB
  f16*    RB    = (f16*)   (ws + (1024u << 10));   // 1 MB
  f16*    W2p   = (f16*)   (ws + (2048u << 10));   // 512 KB
  float*  agg   = (float*) (ws + (2560u << 10));   // 512 KB
  int*    cnt   = (int*)   (ws + (3072u << 10));   // 32 KB
  f16*    Wo1p  = (f16*)   (ws + (3136u << 10));   // 256 KB
  f16*    Wo2p  = (f16*)   (ws + (3392u << 10));   // 512 KB
  f16*    Wo3p  = (f16*)   (ws + (3904u << 10));   // 256 KB
  uint2*  smeta = (uint2*) (ws + (4160u << 10));   // 3 MB -> total ~7.2 MB

  k_prep_all <<<dim3(450),    dim3(256), 0, stream>>>(inputs, W1, b1, W2, Wo1, Wo2, Wo3,
                                                      SA, RB, W2p, Wo1p, Wo2p, Wo3p, cnt, agg);
  k_scatter_d<<<dim3(128),    dim3(512), 0, stream>>>(rec_idx, send_idx, rel, cnt, smeta);
  k_edges    <<<dim3(512, 5), dim3(512), 0, stream>>>(SA, RB, W2p, b2, smeta, cnt, agg);
  k_omlp     <<<dim3(16),     dim3(512), 0, stream>>>(agg, Wo1p, bo1, Wo2p, bo2, Wo3p, bo3, out);
}